// Round 1
// baseline (1589.608 us; speedup 1.0000x reference)
//
#include <hip/hip_runtime.h>
#include <hip/hip_bf16.h>

// VQDistortionLoss: fused cdist -> softmax -> soft-recon -> masked MSE.
// Flash-attention structure: Q=z[N=32768][512], K=V=codebook[4096][512].
// Round 0: correctness-first bf16-MFMA skeleton. Known-slow parts (documented
// for later rounds): recon B-frag scalar u16 LDS gathers (-> ds_read_b64_tr_b16),
// KT=32 (-> 64), f32 codebook staging (-> pre-converted bf16), 4 barriers/ktile.

#define BB 8
#define DD 512
#define TT 4096
#define KKK 4096
#define ENC_STRIDE 320
#define RT 16     // rows per block
#define KT 32     // codes per k-tile
#define NWAVE 4   // waves per block; wave w owns d-slice [128w, 128w+128)

typedef __attribute__((ext_vector_type(8))) short bf16x8;  // 8 bf16 = 4 VGPR
typedef __attribute__((ext_vector_type(4))) float f32x4;   // C/D frag

union FragU { bf16x8 v; uint2 h2[2]; ushort us[8]; };

// f32 -> bf16 RNE (bit-exact with __float2bfloat16 for finite inputs)
static __device__ __forceinline__ ushort f2bf(float x) {
  unsigned u = __float_as_uint(x);
  unsigned r = (u + 0x7FFFu + ((u >> 16) & 1u)) >> 16;
  return (ushort)r;
}
static __device__ __forceinline__ uint2 f4tobf(float4 v) {
  uint2 r;
  r.x = (unsigned)f2bf(v.x) | ((unsigned)f2bf(v.y) << 16);
  r.y = (unsigned)f2bf(v.z) | ((unsigned)f2bf(v.w) << 16);
  return r;
}

// ---- kernel 1: c2[k] = |codebook[k]|^2 ----------------------------------
__global__ __launch_bounds__(256) void vq_c2(const float* __restrict__ cb,
                                             float* __restrict__ c2) {
  int k = blockIdx.x * 4 + (threadIdx.x >> 6);
  int lane = threadIdx.x & 63;
  const float4* p = (const float4*)(cb + (size_t)k * DD + lane * 8);
  float4 a = p[0], b = p[1];
  float s = a.x*a.x + a.y*a.y + a.z*a.z + a.w*a.w
          + b.x*b.x + b.y*b.y + b.z*b.z + b.w*b.w;
  #pragma unroll
  for (int m = 1; m <= 32; m <<= 1) s += __shfl_xor(s, m);
  if (lane == 0) c2[k] = s;
}

// ---- main fused kernel ---------------------------------------------------
// grid = B*T/RT = 2048 blocks of 256 threads (4 waves).
// Assumed A/B k-slot map (kmap): k = (lane>>4)*4 + (i&3) + 16*(i>>2).
// Used consistently for ALL A and B fragments -> any error is a consistent
// permutation of the contraction index and cancels in the MFMA product.
// C/D map (guide-verified m89/m91): col = lane&15, row = (lane>>4)*4 + reg.
__global__ __launch_bounds__(256) void vq_main(
    const float* __restrict__ sf,     // [B][D][T]
    const float* __restrict__ cb,     // [K][D]
    const int*  __restrict__ codes,   // [B][T]
    const int*  __restrict__ lens,    // [B]
    const float* __restrict__ c2,     // [K]
    float* __restrict__ num) {
  // subtiled codebook tile: cs[kblk][dblk*64 + (k&3)*16 + (d&15)], +8 pad/row
  __shared__ ushort cs[8][2056];                 // 32.9 KB
  __shared__ float  sred[NWAVE][RT][KT + 4];     // 9.2 KB  cross-wave score partials
  __shared__ ushort wlds[RT][KT + 8];            // 1.3 KB  softmax weights (bf16)
  __shared__ float  z2red[NWAVE][RT];
  __shared__ float  diffred[RT];

  const int bidx = blockIdx.x;
  const int b  = bidx >> 8;              // T/RT = 256 tiles per batch
  const int t0 = (bidx & 255) << 4;
  const int len = lens[b];
  int vcount = (len + (ENC_STRIDE - 1)) / ENC_STRIDE;   // frames with t*320 < len
  vcount = vcount < TT ? vcount : TT;
  if (t0 >= vcount) return;              // fully masked tile (~45% of blocks)

  const int tid = threadIdx.x;
  const int w  = tid >> 6;
  const int l  = tid & 63;
  const int lg = l >> 4;                 // lane group 0..3
  const int ln = l & 15;                 // row / col within fragment

  if (tid < RT) diffred[tid] = 0.f;

  // ---- load z A-fragments (row = ln, d per kmap) + |z|^2 -----------------
  const float* sfb = sf + (size_t)b * DD * TT;
  const int trow = t0 + ln;
  bf16x8 za[4];
  float z2p = 0.f;
  #pragma unroll
  for (int fi = 0; fi < 4; ++fi) {
    #pragma unroll
    for (int i = 0; i < 8; ++i) {
      int d = w * 128 + fi * 32 + lg * 4 + (i & 3) + 16 * (i >> 2);
      float v = sfb[(size_t)d * TT + trow];
      z2p += v * v;
      za[fi][i] = (short)f2bf(v);
    }
  }
  z2p += __shfl_xor(z2p, 16);
  z2p += __shfl_xor(z2p, 32);
  if (l < 16) z2red[w][ln] = z2p;
  __syncthreads();
  const float z2 = z2red[0][ln] + z2red[1][ln] + z2red[2][ln] + z2red[3][ln];

  // ---- flash state --------------------------------------------------------
  float mrow = -1e30f;    // running max for row ln (replicated across groups)
  float lrow = 0.f;       // running sum
  f32x4 acc[8];           // recon acc: rows x d = [16][w*128 + dt*16 + ln]
  #pragma unroll
  for (int dt = 0; dt < 8; ++dt) acc[dt] = (f32x4){0.f, 0.f, 0.f, 0.f};

  const int sk  = tid >> 3;        // staging: codebook row 0..31
  const int sd8 = tid & 7;
  const int skb = sk >> 2, ska = sk & 3;

  for (int kt0 = 0; kt0 < KKK; kt0 += KT) {
    __syncthreads();               // prev recon done; cs/sred reusable
    // ---- stage codebook tile [KT][512] f32 -> bf16 subtiled --------------
    {
      const float* crow = cb + (size_t)(kt0 + sk) * DD;
      #pragma unroll
      for (int dbl = 0; dbl < 4; ++dbl) {
        int dblk = sd8 + dbl * 8;  // stride-8 dblk: spreads LDS write banks
        const float4* pp = (const float4*)(crow + dblk * 16);
        float4 v0 = pp[0], v1 = pp[1], v2 = pp[2], v3 = pp[3];
        uint2 a0 = f4tobf(v0), a1 = f4tobf(v1), a2 = f4tobf(v2), a3 = f4tobf(v3);
        ushort* dst = &cs[skb][dblk * 64 + ska * 16];
        *(uint4*)(dst)     = make_uint4(a0.x, a0.y, a1.x, a1.y);
        *(uint4*)(dst + 8) = make_uint4(a2.x, a2.y, a3.x, a3.y);
      }
    }
    __syncthreads();               // cs ready

    // ---- scores: S_partial[16 rows][32 codes] over this wave's 128 d -----
    f32x4 sc0 = (f32x4){0,0,0,0}, sc1 = (f32x4){0,0,0,0};
    #pragma unroll
    for (int fi = 0; fi < 4; ++fi) {
      FragU b0, b1;
      #pragma unroll
      for (int h = 0; h < 2; ++h) {
        int off = (w * 8 + fi * 2 + h) * 64 + (ln & 3) * 16 + lg * 4;
        b0.h2[h] = *(const uint2*)&cs[(ln >> 2)][off];
        b1.h2[h] = *(const uint2*)&cs[4 + (ln >> 2)][off];
      }
      sc0 = __builtin_amdgcn_mfma_f32_16x16x32_bf16(za[fi], b0.v, sc0, 0, 0, 0);
      sc1 = __builtin_amdgcn_mfma_f32_16x16x32_bf16(za[fi], b1.v, sc1, 0, 0, 0);
    }
    #pragma unroll
    for (int v = 0; v < 4; ++v) {
      sred[w][lg * 4 + v][ln]      = sc0[v];
      sred[w][lg * 4 + v][16 + ln] = sc1[v];
    }
    __syncthreads();               // sred ready

    // ---- online softmax (redundant in all waves; lane -> row ln, k lg*8..) ----
    const float4* c2p = (const float4*)(c2 + kt0 + lg * 8);
    float4 c2a = c2p[0], c2b = c2p[1];
    float c2v[8] = {c2a.x, c2a.y, c2a.z, c2a.w, c2b.x, c2b.y, c2b.z, c2b.w};
    float s[8];
    {
      float4 d0 = {0,0,0,0}, d1 = {0,0,0,0};
      #pragma unroll
      for (int wv = 0; wv < NWAVE; ++wv) {
        const float4* pr = (const float4*)&sred[wv][ln][lg * 8];
        float4 r0 = pr[0], r1 = pr[1];
        d0.x += r0.x; d0.y += r0.y; d0.z += r0.z; d0.w += r0.w;
        d1.x += r1.x; d1.y += r1.y; d1.z += r1.z; d1.w += r1.w;
      }
      float dot[8] = {d0.x, d0.y, d0.z, d0.w, d1.x, d1.y, d1.z, d1.w};
      #pragma unroll
      for (int j = 0; j < 8; ++j) {
        float d2 = z2 + c2v[j] - 2.f * dot[j];
        s[j] = -sqrtf(fmaxf(d2, 1e-12f));   // TEMPERATURE = 1
      }
    }
    float tmax = s[0];
    #pragma unroll
    for (int j = 1; j < 8; ++j) tmax = fmaxf(tmax, s[j]);
    tmax = fmaxf(tmax, __shfl_xor(tmax, 16));
    tmax = fmaxf(tmax, __shfl_xor(tmax, 32));
    float mnew = fmaxf(mrow, tmax);
    float esum = 0.f;
    ushort eb[8];
    #pragma unroll
    for (int j = 0; j < 8; ++j) {
      float e = __expf(s[j] - mnew);
      esum += e;
      eb[j] = f2bf(e);
    }
    esum += __shfl_xor(esum, 16);
    esum += __shfl_xor(esum, 32);
    float alpha = __expf(mrow - mnew);
    lrow = lrow * alpha + esum;
    mrow = mnew;
    if (w == 0) {
      uint4 pk;
      pk.x = (unsigned)eb[0] | ((unsigned)eb[1] << 16);
      pk.y = (unsigned)eb[2] | ((unsigned)eb[3] << 16);
      pk.z = (unsigned)eb[4] | ((unsigned)eb[5] << 16);
      pk.w = (unsigned)eb[6] | ((unsigned)eb[7] << 16);
      *(uint4*)&wlds[ln][lg * 8] = pk;
    }
    // rescale recon acc rows by alpha[row = lg*4+v]
    #pragma unroll
    for (int v = 0; v < 4; ++v) {
      float av = __shfl(alpha, lg * 4 + v);
      #pragma unroll
      for (int dt = 0; dt < 8; ++dt) acc[dt][v] *= av;
    }
    __syncthreads();               // wlds ready

    // ---- recon: acc[16 rows][128 d] += W[16][32] x C[32][128 slice] ------
    FragU wa;
    wa.h2[0] = *(const uint2*)&wlds[ln][lg * 4];
    wa.h2[1] = *(const uint2*)&wlds[ln][lg * 4 + 16];
    #pragma unroll
    for (int dt = 0; dt < 8; ++dt) {
      FragU cbf;
      #pragma unroll
      for (int h = 0; h < 2; ++h)
        #pragma unroll
        for (int q = 0; q < 4; ++q)   // transposed gather: tr-read upgrade later
          cbf.us[4 * h + q] = cs[lg + 4 * h][(w * 8 + dt) * 64 + q * 16 + ln];
      acc[dt] = __builtin_amdgcn_mfma_f32_16x16x32_bf16(wa.v, cbf.v, acc[dt], 0, 0, 0);
    }
  }

  // ---- epilogue: normalize, MSE vs target embedding, masked accumulate ----
  const int* tcodes = codes + b * TT + t0;
  float pv[4];
  #pragma unroll
  for (int v = 0; v < 4; ++v) {
    int row = lg * 4 + v;
    float lv = __shfl(lrow, row);
    int tc = tcodes[row];
    const float* erow = cb + (size_t)tc * DD;
    float psum = 0.f;
    #pragma unroll
    for (int dt = 0; dt < 8; ++dt) {
      int d = w * 128 + dt * 16 + ln;
      float r = acc[dt][v] / lv;
      float df = r - erow[d];
      psum += df * df;
    }
    pv[v] = psum;
  }
  #pragma unroll
  for (int v = 0; v < 4; ++v) {
    pv[v] += __shfl_xor(pv[v], 1);
    pv[v] += __shfl_xor(pv[v], 2);
    pv[v] += __shfl_xor(pv[v], 4);
    pv[v] += __shfl_xor(pv[v], 8);
  }
  if (ln == 0) {
    #pragma unroll
    for (int v = 0; v < 4; ++v) atomicAdd(&diffred[lg * 4 + v], pv[v]);
  }
  __syncthreads();
  if (tid < RT) {
    float val = (t0 + tid < vcount) ? diffred[tid] * (1.f / DD) : 0.f;
    val += __shfl_xor(val, 1);
    val += __shfl_xor(val, 2);
    val += __shfl_xor(val, 4);
    val += __shfl_xor(val, 8);
    if (tid == 0) atomicAdd(num, val);
  }
}

// ---- finalize: loss = num / (sum(mask) + 1e-8) ---------------------------
__global__ void vq_finalize(const float* __restrict__ num,
                            const int* __restrict__ lens,
                            float* __restrict__ out) {
  float denom = 0.f;
  for (int b = 0; b < BB; ++b) {
    int v = (lens[b] + (ENC_STRIDE - 1)) / ENC_STRIDE;
    v = v < TT ? v : TT;
    denom += (float)v;
  }
  out[0] = num[0] / (denom + 1e-8f);
}

extern "C" void kernel_launch(void* const* d_in, const int* in_sizes, int n_in,
                              void* d_out, int out_size, void* d_ws, size_t ws_size,
                              hipStream_t stream) {
  const float* sf    = (const float*)d_in[0];
  const float* cb    = (const float*)d_in[1];
  const int*   codes = (const int*)d_in[2];
  const int*   lens  = (const int*)d_in[3];
  float* out = (float*)d_out;
  float* num = (float*)d_ws;                        // [0]: loss numerator
  float* c2  = (float*)((char*)d_ws + 256);         // [4096] f32 row norms

  hipMemsetAsync(d_ws, 0, 4, stream);
  vq_c2<<<KKK / 4, 256, 0, stream>>>(cb, c2);
  vq_main<<<(BB * TT) / RT, 256, 0, stream>>>(sf, cb, codes, lens, c2, num);
  vq_finalize<<<1, 1, 0, stream>>>(num, lens, out);
}

// Round 2
// 1026.013 us; speedup vs baseline: 1.5493x; 1.5493x over previous
//
#include <hip/hip_runtime.h>
#include <hip/hip_bf16.h>

// VQDistortionLoss: fused cdist -> softmax -> soft-recon -> masked MSE.
// R2: (1) ds_read_b64_tr_b16 for recon B-frags (was 64 conflicted u16 gathers),
//     (2) pre-converted bf16 codebook in ws + global_load_lds width-16 staging
//         (ws_size-guarded, fallback = in-kernel cvt),
//     (3) wlds LDS round-trip removed (softmax lanes re-mapped to own-frag codes),
//         3 barriers/ktile.

#define BB 8
#define DD 512
#define TT 4096
#define KKK 4096
#define ENC_STRIDE 320
#define RT 16     // rows per block
#define KT 32     // codes per k-tile
#define NWAVE 4   // wave w owns d-slice [128w, 128w+128)

typedef __attribute__((ext_vector_type(8))) short bf16x8;  // 8 bf16 = 4 VGPR
typedef __attribute__((ext_vector_type(4))) float f32x4;   // C/D frag

union FragU { bf16x8 v; uint2 h2[2]; ushort us[8]; unsigned long long q[2]; };

// f32 -> bf16 RNE
static __device__ __forceinline__ ushort f2bf(float x) {
  unsigned u = __float_as_uint(x);
  unsigned r = (u + 0x7FFFu + ((u >> 16) & 1u)) >> 16;
  return (ushort)r;
}
static __device__ __forceinline__ uint2 f4tobf(float4 v) {
  uint2 r;
  r.x = (unsigned)f2bf(v.x) | ((unsigned)f2bf(v.y) << 16);
  r.y = (unsigned)f2bf(v.z) | ((unsigned)f2bf(v.w) << 16);
  return r;
}

// global -> LDS direct DMA, 16B/lane; LDS dest = uniform base + lane*16
static __device__ __forceinline__ void gld_lds16(const void* g, void* l) {
  __builtin_amdgcn_global_load_lds(
      (const __attribute__((address_space(1))) unsigned*)g,
      (__attribute__((address_space(3))) unsigned*)l, 16, 0, 0);
}
// generic LDS pointer -> 32-bit LDS byte offset (for inline-asm ds ops)
static __device__ __forceinline__ unsigned lds_addr(const void* p) {
  return (unsigned)(size_t)(const __attribute__((address_space(3))) char*)p;
}

// ---- prep: c2[k] = |codebook[k]|^2, cbh = bf16 codebook ------------------
__global__ __launch_bounds__(256) void vq_prep(const float* __restrict__ cb,
                                               float* __restrict__ c2,
                                               ushort* __restrict__ cbh) {
  int k = blockIdx.x * 4 + (threadIdx.x >> 6);
  int lane = threadIdx.x & 63;
  const float4* p = (const float4*)(cb + (size_t)k * DD + lane * 8);
  float4 a = p[0], b = p[1];
  if (cbh) {
    uint2 pa = f4tobf(a), pb = f4tobf(b);
    *(uint4*)(cbh + (size_t)k * DD + lane * 8) = make_uint4(pa.x, pa.y, pb.x, pb.y);
  }
  float s = a.x*a.x + a.y*a.y + a.z*a.z + a.w*a.w
          + b.x*b.x + b.y*b.y + b.z*b.z + b.w*b.w;
  #pragma unroll
  for (int m = 1; m <= 32; m <<= 1) s += __shfl_xor(s, m);
  if (lane == 0) c2[k] = s;
}

// ---- main fused kernel ---------------------------------------------------
// cs layout (bf16, no pad; rows are 4096B = 4 linear 1024B gload chunks):
//   cs[kb][db*64 + ka*16 + dl] = C[kb*4+ka][db*16+dl]
// A/B k-slot map (kmap, self-consistent): k = lg*4 + (i&3) + 16*(i>>2).
// C/D map (verified m89/m91): col = lane&15, row = lg*4 + reg.
template <int PRECONV>
__global__ __launch_bounds__(256) void vq_main(
    const float* __restrict__ sf,     // [B][D][T] f32
    const float* __restrict__ cb,     // [K][D] f32
    const ushort* __restrict__ cbh,   // [K][D] bf16 (PRECONV only)
    const int*  __restrict__ codes,   // [B][T]
    const int*  __restrict__ lens,    // [B]
    const float* __restrict__ c2,     // [K]
    float* __restrict__ num) {
  __shared__ __align__(128) ushort cs[8][2048];        // 32 KB
  __shared__ __align__(16) float sred[NWAVE][RT][36];  // 9.2 KB score partials
  __shared__ float z2red[NWAVE][RT];
  __shared__ float diffred[RT];

  const int bidx = blockIdx.x;
  const int b  = bidx >> 8;
  const int t0 = (bidx & 255) << 4;
  const int len = lens[b];
  int vcount = (len + (ENC_STRIDE - 1)) / ENC_STRIDE;
  vcount = vcount < TT ? vcount : TT;
  if (t0 >= vcount) return;

  const int tid = threadIdx.x;
  const int w  = tid >> 6;
  const int l  = tid & 63;
  const int lg = l >> 4;
  const int ln = l & 15;

  if (tid < RT) diffred[tid] = 0.f;

  // ---- z A-fragments (row = ln, d per kmap) + |z|^2 ----------------------
  const float* sfb = sf + (size_t)b * DD * TT;
  const int trow = t0 + ln;
  bf16x8 za[4];
  float z2p = 0.f;
  #pragma unroll
  for (int fi = 0; fi < 4; ++fi) {
    #pragma unroll
    for (int i = 0; i < 8; ++i) {
      int d = w * 128 + fi * 32 + lg * 4 + (i & 3) + 16 * (i >> 2);
      float v = sfb[(size_t)d * TT + trow];
      z2p += v * v;
      za[fi][i] = (short)f2bf(v);
    }
  }
  z2p += __shfl_xor(z2p, 16);
  z2p += __shfl_xor(z2p, 32);
  if (l < 16) z2red[w][ln] = z2p;
  __syncthreads();
  const float z2 = z2red[0][ln] + z2red[1][ln] + z2red[2][ln] + z2red[3][ln];

  float mrow = -1e30f, lrow = 0.f;
  f32x4 acc[8];
  #pragma unroll
  for (int dt = 0; dt < 8; ++dt) acc[dt] = (f32x4){0.f, 0.f, 0.f, 0.f};

  // staging lane constants
  const unsigned lane_code = (l >> 1) & 3;                     // PRECONV path
  const unsigned lane_d    = ((l >> 3) << 4) + ((l & 1) << 3);
  const int sk = tid >> 3, sd8 = tid & 7;                      // fallback path
  const int skb = sk >> 2, ska = sk & 3;

  const unsigned tr_base = lds_addr(&cs[0][0]) + ((lg * 2048 + w * 512 + ln * 4) << 1);

  for (int kt0 = 0; kt0 < KKK; kt0 += KT) {
    __syncthreads();               // [A] prev recon/softmax done; cs,sred reusable
    if (PRECONV) {
      const ushort* base = cbh + (size_t)kt0 * DD;
      ushort* lbase = &cs[0][0];
      #pragma unroll
      for (int j = 0; j < 8; ++j) {
        int t = w * 8 + j;
        gld_lds16(base + (size_t)((t >> 2) * 4 + lane_code) * DD + (t & 3) * 128 + lane_d,
                  lbase + t * 512);
      }
    } else {
      const float* crow = cb + (size_t)(kt0 + sk) * DD;
      #pragma unroll
      for (int dbl = 0; dbl < 4; ++dbl) {
        int dblk = sd8 + dbl * 8;
        const float4* pp = (const float4*)(crow + dblk * 16);
        float4 v0 = pp[0], v1 = pp[1], v2 = pp[2], v3 = pp[3];
        uint2 a0 = f4tobf(v0), a1 = f4tobf(v1), a2 = f4tobf(v2), a3 = f4tobf(v3);
        ushort* dst = &cs[skb][dblk * 64 + ska * 16];
        *(uint4*)(dst)     = make_uint4(a0.x, a0.y, a1.x, a1.y);
        *(uint4*)(dst + 8) = make_uint4(a2.x, a2.y, a3.x, a3.y);
      }
    }
    __syncthreads();               // [B] cs ready (compiler drains vmcnt here)

    // ---- scores over this wave's 128-d slice -----------------------------
    f32x4 sc0 = (f32x4){0,0,0,0}, sc1 = (f32x4){0,0,0,0};
    #pragma unroll
    for (int fi = 0; fi < 4; ++fi) {
      FragU b0, b1;
      #pragma unroll
      for (int h = 0; h < 2; ++h) {
        int off = (w * 8 + fi * 2 + h) * 64 + (ln & 3) * 16 + lg * 4;
        b0.h2[h] = *(const uint2*)&cs[(ln >> 2)][off];
        b1.h2[h] = *(const uint2*)&cs[4 + (ln >> 2)][off];
      }
      sc0 = __builtin_amdgcn_mfma_f32_16x16x32_bf16(za[fi], b0.v, sc0, 0, 0, 0);
      sc1 = __builtin_amdgcn_mfma_f32_16x16x32_bf16(za[fi], b1.v, sc1, 0, 0, 0);
    }
    #pragma unroll
    for (int v = 0; v < 4; ++v) {
      sred[w][lg * 4 + v][ln]      = sc0[v];
      sred[w][lg * 4 + v][16 + ln] = sc1[v];
    }
    __syncthreads();               // [C] sred ready

    // ---- softmax: lane handles row ln, codes {lg*4+q, 16+lg*4+q} ---------
    // (exactly the codes of this lane's recon A-fragment -> no W round-trip)
    float4 c2a = *(const float4*)(c2 + kt0 + lg * 4);
    float4 c2b = *(const float4*)(c2 + kt0 + 16 + lg * 4);
    float4 d0 = {0,0,0,0}, d1 = {0,0,0,0};
    #pragma unroll
    for (int wv = 0; wv < NWAVE; ++wv) {
      float4 r0 = *(const float4*)&sred[wv][ln][lg * 4];
      float4 r1 = *(const float4*)&sred[wv][ln][16 + lg * 4];
      d0.x += r0.x; d0.y += r0.y; d0.z += r0.z; d0.w += r0.w;
      d1.x += r1.x; d1.y += r1.y; d1.z += r1.z; d1.w += r1.w;
    }
    float dot[8] = {d0.x, d0.y, d0.z, d0.w, d1.x, d1.y, d1.z, d1.w};
    float c2v[8] = {c2a.x, c2a.y, c2a.z, c2a.w, c2b.x, c2b.y, c2b.z, c2b.w};
    float s[8];
    #pragma unroll
    for (int j = 0; j < 8; ++j) {
      float d2 = z2 + c2v[j] - 2.f * dot[j];
      s[j] = -sqrtf(fmaxf(d2, 1e-12f));   // TEMPERATURE = 1
    }
    float tmax = s[0];
    #pragma unroll
    for (int j = 1; j < 8; ++j) tmax = fmaxf(tmax, s[j]);
    tmax = fmaxf(tmax, __shfl_xor(tmax, 16));
    tmax = fmaxf(tmax, __shfl_xor(tmax, 32));
    float mnew = fmaxf(mrow, tmax);
    float esum = 0.f;
    FragU wa;
    #pragma unroll
    for (int j = 0; j < 8; ++j) {
      float e = __expf(s[j] - mnew);
      esum += e;
      wa.us[j] = f2bf(e);          // slot j == kmap(j)'s code by construction
    }
    esum += __shfl_xor(esum, 16);
    esum += __shfl_xor(esum, 32);
    float alpha = __expf(mrow - mnew);
    lrow = lrow * alpha + esum;
    mrow = mnew;
    #pragma unroll
    for (int v = 0; v < 4; ++v) {
      float av = __shfl(alpha, lg * 4 + v);
      #pragma unroll
      for (int dt = 0; dt < 8; ++dt) acc[dt][v] *= av;
    }

    // ---- recon: B-frags via hardware transpose reads ---------------------
    // group lg reads 4x16 tile at cs row (lg+4h), subtile (w*8+dt):
    //   elem j = C[(lg+4h)*4 + j][(w*8+dt)*16 + ln] == kmap slot 4h+j. (T10)
    unsigned long long tq0[8], tq1[8];
    #pragma unroll
    for (int dt = 0; dt < 8; ++dt) {
      asm volatile("ds_read_b64_tr_b16 %0, %2 offset:%3\n\t"
                   "ds_read_b64_tr_b16 %1, %2 offset:%4"
                   : "=&v"(tq0[dt]), "=&v"(tq1[dt])
                   : "v"(tr_base), "i"(dt * 128), "i"(16384 + dt * 128));
    }
    asm volatile("s_waitcnt lgkmcnt(0)" ::: "memory");
    __builtin_amdgcn_sched_barrier(0);   // rule #18: pin MFMAs after the wait
    #pragma unroll
    for (int dt = 0; dt < 8; ++dt) {
      FragU cbf;
      cbf.q[0] = tq0[dt];
      cbf.q[1] = tq1[dt];
      acc[dt] = __builtin_amdgcn_mfma_f32_16x16x32_bf16(wa.v, cbf.v, acc[dt], 0, 0, 0);
    }
  }

  // ---- epilogue -----------------------------------------------------------
  const int* tcodes = codes + b * TT + t0;
  float pv[4];
  #pragma unroll
  for (int v = 0; v < 4; ++v) {
    int row = lg * 4 + v;
    float lv = __shfl(lrow, row);
    int tc = tcodes[row];
    const float* erow = cb + (size_t)tc * DD;
    float psum = 0.f;
    #pragma unroll
    for (int dt = 0; dt < 8; ++dt) {
      int d = w * 128 + dt * 16 + ln;
      float r = acc[dt][v] / lv;
      float df = r - erow[d];
      psum += df * df;
    }
    pv[v] = psum;
  }
  #pragma unroll
  for (int v = 0; v < 4; ++v) {
    pv[v] += __shfl_xor(pv[v], 1);
    pv[v] += __shfl_xor(pv[v], 2);
    pv[v] += __shfl_xor(pv[v], 4);
    pv[v] += __shfl_xor(pv[v], 8);
  }
  if (ln == 0) {
    #pragma unroll
    for (int v = 0; v < 4; ++v) atomicAdd(&diffred[lg * 4 + v], pv[v]);
  }
  __syncthreads();
  if (tid < RT) {
    float val = (t0 + tid < vcount) ? diffred[tid] * (1.f / DD) : 0.f;
    val += __shfl_xor(val, 1);
    val += __shfl_xor(val, 2);
    val += __shfl_xor(val, 4);
    val += __shfl_xor(val, 8);
    if (tid == 0) atomicAdd(num, val);
  }
}

// ---- finalize: loss = num / (sum(mask) + 1e-8) ---------------------------
__global__ void vq_finalize(const float* __restrict__ num,
                            const int* __restrict__ lens,
                            float* __restrict__ out) {
  float denom = 0.f;
  for (int b = 0; b < BB; ++b) {
    int v = (lens[b] + (ENC_STRIDE - 1)) / ENC_STRIDE;
    v = v < TT ? v : TT;
    denom += (float)v;
  }
  out[0] = num[0] / (denom + 1e-8f);
}

extern "C" void kernel_launch(void* const* d_in, const int* in_sizes, int n_in,
                              void* d_out, int out_size, void* d_ws, size_t ws_size,
                              hipStream_t stream) {
  const float* sf    = (const float*)d_in[0];
  const float* cb    = (const float*)d_in[1];
  const int*   codes = (const int*)d_in[2];
  const int*   lens  = (const int*)d_in[3];
  float* out = (float*)d_out;
  float* num = (float*)d_ws;                        // [0]: loss numerator
  float* c2  = (float*)((char*)d_ws + 256);         // [4096] f32
  const size_t need = 32768 + (size_t)KKK * DD * sizeof(ushort);
  ushort* cbh = (ws_size >= need) ? (ushort*)((char*)d_ws + 32768) : nullptr;

  hipMemsetAsync(d_ws, 0, 4, stream);
  vq_prep<<<KKK / 4, 256, 0, stream>>>(cb, c2, cbh);
  if (cbh)
    vq_main<1><<<(BB * TT) / RT, 256, 0, stream>>>(sf, cb, cbh, codes, lens, c2, num);
  else
    vq_main<0><<<(BB * TT) / RT, 256, 0, stream>>>(sf, cb, cbh, codes, lens, c2, num);
  vq_finalize<<<1, 1, 0, stream>>>(num, lens, out);
}